// Round 9
// baseline (1384.874 us; speedup 1.0000x reference)
//
#include <hip/hip_runtime.h>
#include <math.h>

#define TS 10
#define TD 128
#define TE 64
#define BT 8
#define NTHR 256
#define HSTR 132          // floats per Hs row: 128+4 pad
#define QSTR 68           // floats per Q/K/Vd/G/t row: 64+4 pad
#define NHROWS (TS*BT)    // 80

#define HS_FLOATS (NHROWS*HSTR)    // 10560
#define BUF_FLOATS (40*QSTR)       // 2720 (half-batch 40-row buffer)
#define P_FLOATS (BT*TS*12)        // 960
#define LDS_FLOATS (HS_FLOATS + 3*BUF_FLOATS + P_FLOATS)   // 19680 -> 78720 B (2 WG/CU)

#define INVSQRT10 0.31622776601683794f

typedef float v2f __attribute__((ext_vector_type(2)));

// ---------------- pre-kernel (once per launch, into d_ws) -------------------
// ws layout: [0,1280) POS[10][128];  [1280,6400) Z[n][c][j] (10 x 4 x 128).
//   P2[n][c][i] = sum_d qout2[n][i][d] * UL_w[d][c]        (held in registers)
//   Z[n][c][j]  = sum_i qin2[n][j][i] * P2[n][c][i]
// so out[b][n][c] = sum_j E22[b][n][j] * Z[n][c][j] — the entire layer-2
// quesin2/quesout2/UL_w pipeline collapses into one K=128 dot per output
// (-16.2% of kernel FMAs, -654KB/WG of weight streaming).
__global__ void pre_kernel(float* __restrict__ ws,
                           const float* __restrict__ qin2,
                           const float* __restrict__ qout2,
                           const float* __restrict__ UL_w) {
    int tid = threadIdx.x;
    for (int idx = tid; idx < TS * TD; idx += 256) {
        int n = idx / TD, d = idx % TD;
        int j = d >> 1;
        double ang = (double)n / pow(1000.0, 2.0 * (double)j / (double)TD);
        double v = (d & 1) ? cos(ang) : sin(ang);
        ws[idx] = (float)v;
    }
    if (tid < TS * 4) {
        int n = tid >> 2, c = tid & 3;
        float p2r[TE];
#pragma unroll 4
        for (int i = 0; i < TE; i++) {
            const float* qp = qout2 + ((size_t)n * TE + i) * TD;
            float acc = 0.f;
            for (int d = 0; d < TD; d += 4) {
                float4 q4 = *(const float4*)(qp + d);
                acc = fmaf(q4.x, UL_w[(d + 0) * 4 + c], acc);
                acc = fmaf(q4.y, UL_w[(d + 1) * 4 + c], acc);
                acc = fmaf(q4.z, UL_w[(d + 2) * 4 + c], acc);
                acc = fmaf(q4.w, UL_w[(d + 3) * 4 + c], acc);
            }
            p2r[i] = acc;
        }
        float* zr = ws + TS * TD + (n * 4 + c) * TD;
#pragma unroll 4
        for (int j = 0; j < TD; j++) {
            const float* ip = qin2 + ((size_t)n * TD + j) * TE;
            float acc = 0.f;
            for (int i = 0; i < TE; i += 4) {
                float4 q4 = *(const float4*)(ip + i);
                acc = fmaf(q4.x, p2r[i + 0], acc);
                acc = fmaf(q4.y, p2r[i + 1], acc);
                acc = fmaf(q4.z, p2r[i + 2], acc);
                acc = fmaf(q4.w, p2r[i + 3], acc);
            }
            zr[j] = acc;
        }
    }
}

// ---------------- M-row x C-col fp32 GEMM tile, packed-pair FMAs ------------
// OUT[m][c] = sum_k A[row(m)+k] * W[k*ws+c]. A,O in LDS; W in global.
// K multiple of 16. Deep W-prefetch (R5/R6-proven): W loads issue a full 8-k
// block (~256 compute-cycles at M=8/C=4) before first use, covering ~200cyc
// L2-hit latency. A is a 4-k LDS double-buffer (~120cyc <= 128cyc cover).
template <int M, int SPLIT, int C, int K, bool ADD>
__device__ __forceinline__ void gemm_f32(
    const float* __restrict__ Ap, int a0, int aHi, int aLo,
    const float* __restrict__ W, int ws,
    float* __restrict__ Op, int o0, int oHi, int oLo,
    float scale)
{
    static_assert(C % 4 == 0, "C must be a multiple of 4");
    static_assert(K % 16 == 0 && K >= 32, "K must be a multiple of 16, >=32");
    constexpr int CG = C / 4;   // float4 groups
    constexpr int CP = C / 2;   // float2 pairs
    v2f acc[M][CP];
#pragma unroll
    for (int m = 0; m < M; m++)
#pragma unroll
        for (int p = 0; p < CP; p++) acc[m][p] = (v2f)(0.f);

    float4 aR0[M], aR1[M];
    float4 wA[8 * CG], wB[8 * CG];      // ping-pong 8-k W buffers
    const float* ap = Ap + a0;
    const float* wp = W;

    auto loadW8 = [&](float4* wR, const float* w) {
#pragma unroll
        for (int kk = 0; kk < 8; kk++)
#pragma unroll
            for (int cg = 0; cg < CG; cg++)
                wR[kk * CG + cg] = *(const float4*)(w + kk * ws + cg * 4);
    };
    auto loadA = [&](float4* aR, const float* a) {
#pragma unroll
        for (int m = 0; m < M; m++)
            aR[m] = *(const float4*)(a + (m / SPLIT) * aHi + (m % SPLIT) * aLo);
    };
    // 4 consecutive k-steps from wR[0..4*CG)
    auto computeH = [&](const float4* aR, const float4* wR) {
#pragma unroll
        for (int m = 0; m < M; m++) {
            const float* af = (const float*)&aR[m];
#pragma unroll
            for (int kk = 0; kk < 4; kk++) {
                v2f av; av.x = af[kk]; av.y = af[kk];
                const v2f* wf = (const v2f*)&wR[kk * CG];
#pragma unroll
                for (int p = 0; p < CP; p++)
                    acc[m][p] = av * wf[p] + acc[m][p];   // v_pk_fma_f32
            }
        }
    };

    loadW8(wA, wp);          // k rows 0..7
    loadA(aR0, ap);          // k 0..3
#pragma unroll 1
    for (int k = 0; k + 16 < K; k += 16) {
        loadW8(wB, wp + 8 * ws);        // rows k+8..k+15 (used 2 computeH later)
        loadA(aR1, ap + 4);             // k+4..7
        computeH(aR0, wA);              // k..k+3
        loadA(aR0, ap + 8);             // k+8..11
        computeH(aR1, wA + 4 * CG);     // k+4..7
        loadW8(wA, wp + 16 * ws);       // rows k+16..k+23 (next iter / tail)
        loadA(aR1, ap + 12);            // k+12..15
        computeH(aR0, wB);              // k+8..11
        loadA(aR0, ap + 16);            // k+16..19
        computeH(aR1, wB + 4 * CG);     // k+12..15
        wp += 16 * ws; ap += 16;
    }
    // tail: final 16 k-steps (wA = rows k..k+7, aR0 = k..k+3)
    loadW8(wB, wp + 8 * ws);
    loadA(aR1, ap + 4);
    computeH(aR0, wA);
    loadA(aR0, ap + 8);
    computeH(aR1, wA + 4 * CG);
    loadA(aR1, ap + 12);
    computeH(aR0, wB);
    computeH(aR1, wB + 4 * CG);

    v2f s2; s2.x = scale; s2.y = scale;
#pragma unroll
    for (int m = 0; m < M; m++) {
        float* op = Op + o0 + (m / SPLIT) * oHi + (m % SPLIT) * oLo;
#pragma unroll
        for (int cg = 0; cg < CG; cg++) {
            float4 r;
            v2f* rp = (v2f*)&r;
            if constexpr (ADD) {
                float4 v = *(float4*)(op + cg * 4);
                const v2f* vp = (const v2f*)&v;
                rp[0] = s2 * acc[m][cg * 2 + 0] + vp[0];
                rp[1] = s2 * acc[m][cg * 2 + 1] + vp[1];
            } else {
                rp[0] = s2 * acc[m][cg * 2 + 0];
                rp[1] = s2 * acc[m][cg * 2 + 1];
            }
            *(float4*)(op + cg * 4) = r;
        }
    }
}

// ---------------- fused kernel ----------------------------------------------
// BT=8, hb-split, 78.72 KB LDS -> 2 WG/CU (LDS-limited), REQUIRES VGPR<=128
// (residency cliff at 128/129 — R5). launch_bounds(256,2) pins the cap at 128
// (R0/R6-proven); arg>=4 caps at 64 and spills catastrophically (R1/R3).
// R9: layer-2 quesin2/quesout2/UL pipeline replaced by precomputed Z dots.
extern "C" __global__ __launch_bounds__(NTHR, 2)
void trans_fused(const float* __restrict__ x,
                 const float* __restrict__ L_w, const float* __restrict__ UL_w,
                 const float* __restrict__ WQ,  const float* __restrict__ WK,
                 const float* __restrict__ WVd, const float* __restrict__ WVu,
                 const float* __restrict__ WQ2, const float* __restrict__ WK2,
                 const float* __restrict__ WVd2,const float* __restrict__ WVu2,
                 const float* __restrict__ qin1,const float* __restrict__ qout1,
                 const float* __restrict__ qin2,const float* __restrict__ qout2,
                 const float* __restrict__ POSb, float* __restrict__ out)
{
    extern __shared__ float lds[];
    float* Hs = lds;                      // [80][HSTR], row = b*10 + n
    float* Qb = lds + HS_FLOATS;          // [40][QSTR], row r2 = b4*10 + n ; also G, t(lo)
    float* Kb = Qb + BUF_FLOATS;          // [40][QSTR]                     ; also t(hi)
    float* Vb = Kb + BUF_FLOATS;          // [40][QSTR] Vd
    float* Pb = Vb + BUF_FLOATS;          // [8][10][12] logits -> softmax weights
    float* Tb = Qb;                       // t: 80 rows spanning Qb+Kb

    const int tid = threadIdx.x;
    const int vtid = (tid + ((blockIdx.x & 3) << 6)) & 255;  // rotate idle windows
    const int gb0 = blockIdx.x * BT;
    const float* Zb = POSb + TS * TD;     // Z[n][c][j] (10 x 4 x 128)

    // ---- Phase 0: h = x @ L_w + POS (fp32; 4-term dot, packed) ----
    for (int idx = tid; idx < NHROWS * 32; idx += NTHR) {
        int r = idx >> 5, dg = (idx & 31) << 2;
        int b = r / 10, n = r - b * 10;
        const float* xp = x + ((size_t)(gb0 + b) * TS + n) * 4;
        float4 xv = *(const float4*)xp;
        const float* xf = (const float*)&xv;
        float4 p4 = *(const float4*)(POSb + n * TD + dg);
        v2f acc0 = ((const v2f*)&p4)[0], acc1 = ((const v2f*)&p4)[1];
#pragma unroll
        for (int c = 0; c < 4; c++) {
            float4 lw = *(const float4*)(L_w + c * TD + dg);
            v2f xb; xb.x = xf[c]; xb.y = xf[c];
            acc0 = xb * ((const v2f*)&lw)[0] + acc0;
            acc1 = xb * ((const v2f*)&lw)[1] + acc1;
        }
        float4 r4;
        ((v2f*)&r4)[0] = acc0; ((v2f*)&r4)[1] = acc1;
        *(float4*)(Hs + r * HSTR + dg) = r4;
    }
    __syncthreads();

    for (int layer = 0; layer < 2; ++layer) {
        const float* pWQ  = layer ? WQ2  : WQ;
        const float* pWK  = layer ? WK2  : WK;
        const float* pWVd = layer ? WVd2 : WVd;
        const float* pWVu = layer ? WVu2 : WVu;

        for (int hb = 0; hb < 2; ++hb) {
            // batches b = hb*4 + b4; Hs rows (hb*4+b4)*10 + n
            // ---- QKV: 240 tasks = mat(3) x np(5) x cg(16); M=8 = b4(4) x (n,n+5) ----
            if (vtid < 240) {
                int p = vtid / 80, t2 = vtid % 80;
                int np = t2 >> 4, cg = t2 & 15;
                const float* Wp = (p == 0 ? pWQ : (p == 1 ? pWK : pWVd)) + cg * 4;
                float* Ob = (p == 0 ? Qb : (p == 1 ? Kb : Vb));
                gemm_f32<8, 2, 4, TD, false>(
                    Hs, (hb * 40 + np) * HSTR, 10 * HSTR, 5 * HSTR,
                    Wp, TE,
                    Ob, np * QSTR + cg * 4, 10 * QSTR, 5 * QSTR, 1.f);
            }
            __syncthreads();

            // ---- logits (fp32, 2x2 packed chains): 220 = b4(4) x 55 (i,j<=i) ----
            if (vtid < 220) {
                int b4 = vtid / 55, pr = vtid % 55;
                int i = 0, base = 0;
                while (pr >= base + i + 1) { base += i + 1; i++; }
                int j = pr - base;
                const float* qr = Qb + (b4 * 10 + i) * QSTR;
                const float* kr = Kb + (b4 * 10 + j) * QSTR;
                v2f s0 = (v2f)(0.f), s1 = (v2f)(0.f);
                for (int e = 0; e < TE; e += 8) {
                    float4 qa = *(const float4*)(qr + e);
                    float4 ka = *(const float4*)(kr + e);
                    float4 qc = *(const float4*)(qr + e + 4);
                    float4 kc = *(const float4*)(kr + e + 4);
                    s0 = ((const v2f*)&qa)[0] * ((const v2f*)&ka)[0] + s0;
                    s1 = ((const v2f*)&qa)[1] * ((const v2f*)&ka)[1] + s1;
                    s0 = ((const v2f*)&qc)[0] * ((const v2f*)&kc)[0] + s0;
                    s1 = ((const v2f*)&qc)[1] * ((const v2f*)&kc)[1] + s1;
                }
                Pb[(hb * 4 + b4) * 120 + i * 12 + j] = (s0.x + s0.y) + (s1.x + s1.y);
            }
            __syncthreads();

            // ---- softmax over keys j<=i (fp32, matches reference) ----
            if (vtid < 40) {
                int b4 = vtid / 10, i = vtid % 10;
                float* pr = Pb + (hb * 4 + b4) * 120 + i * 12;
                float m = pr[0];
#pragma unroll
                for (int j = 1; j < TS; j++) if (j <= i) m = fmaxf(m, pr[j]);
                float sum = 0.f;
#pragma unroll
                for (int j = 0; j < TS; j++) if (j <= i) { float e = expf(pr[j] - m); pr[j] = e; sum += e; }
#pragma unroll
                for (int j = 0; j < TS; j++) pr[j] = (j <= i) ? pr[j] / sum : 0.f;
            }
            __syncthreads();

            // ---- G[r2=b4*10+q][e] = sum_k P * Vd[b4*10+k][e]; into Qb (Q dead) ----
            for (int oi = vtid; oi < 40 * 16; oi += NTHR) {
                int rr = oi >> 4, e4 = (oi & 15) * 4;
                int b4 = rr / 10, q = rr - b4 * 10;
                const float* pp = Pb + (hb * 4 + b4) * 120 + q * 12;
                v2f g0 = (v2f)(0.f), g1 = (v2f)(0.f);
#pragma unroll
                for (int k = 0; k < TS; k++) {
                    float p = pp[k];
                    v2f pv; pv.x = p; pv.y = p;
                    float4 v = *(const float4*)(Vb + (b4 * 10 + k) * QSTR + e4);
                    g0 = pv * ((const v2f*)&v)[0] + g0;
                    g1 = pv * ((const v2f*)&v)[1] + g1;
                }
                float4 g;
                ((v2f*)&g)[0] = g0; ((v2f*)&g)[1] = g1;
                *(float4*)(Qb + rr * QSTR + e4) = g;
            }
            __syncthreads();

            // ---- DE: Hs(half) += invsqrt10 * G @ WVu ----
            // 256 tasks exactly: b4(4) x qp(2) x cg(32); M=5 contiguous q rows.
            {
                int b4 = vtid >> 6, t2 = vtid & 63;
                int qp = t2 >> 5, cg = t2 & 31;
                gemm_f32<5, 5, 4, TE, true>(
                    Qb, (b4 * 10 + qp * 5) * QSTR, 0, QSTR,
                    pWVu + cg * 4, TD,
                    Hs, (hb * 40 + b4 * 10 + qp * 5) * HSTR + cg * 4, 0, HSTR,
                    INVSQRT10);
            }
            __syncthreads();
        } // hb

        if (layer == 0) {
            // ---- ques-in: t[80][64] = Hs @ quesin1[n]; 160 = n(10) x cg(16), M=8 ----
            if (vtid < 160) {
                int n = vtid >> 4, cg = vtid & 15;
                gemm_f32<8, 1, 4, TD, false>(
                    Hs, n * HSTR, 10 * HSTR, 0,
                    qin1 + (size_t)n * TD * TE + cg * 4, TE,
                    Tb, n * QSTR + cg * 4, 10 * QSTR, 0, 1.f);
            }
            __syncthreads();

            // ---- ques-out: Hs = t @ quesout1[n]; 320 = n(10) x cg(32), M=8 C=4 ----
            for (int task = vtid; task < 320; task += NTHR) {
                int n = task >> 5, cg = task & 31;
                gemm_f32<8, 1, 4, TE, false>(
                    Tb, n * QSTR, 10 * QSTR, 0,
                    qout1 + (size_t)n * TE * TD + cg * 4, TD,
                    Hs, n * HSTR + cg * 4, 10 * HSTR, 0, 1.f);
            }
            __syncthreads();
        } else {
            // ---- out[b][n][c] = E22 row . Z[n][c][:] (K=128); 320 tasks ----
            for (int idx = vtid; idx < NHROWS * 4; idx += NTHR) {
                int r = idx >> 2, c = idx & 3;
                int b = r / 10, n = r - b * 10;
                const float* hr = Hs + r * HSTR;
                const float* zr = Zb + (n * 4 + c) * TD;
                v2f s0 = (v2f)(0.f), s1 = (v2f)(0.f);
                for (int d = 0; d < TD; d += 4) {
                    float4 h4 = *(const float4*)(hr + d);
                    float4 z4 = *(const float4*)(zr + d);
                    s0 = ((const v2f*)&h4)[0] * ((const v2f*)&z4)[0] + s0;
                    s1 = ((const v2f*)&h4)[1] * ((const v2f*)&z4)[1] + s1;
                }
                out[((size_t)(gb0 + b) * TS + n) * 4 + c] = (s0.x + s0.y) + (s1.x + s1.y);
            }
        }
    } // layer
}

// ---------------- host launch -----------------------------------------------
extern "C" void kernel_launch(void* const* d_in, const int* in_sizes, int n_in,
                              void* d_out, int out_size, void* d_ws, size_t ws_size,
                              hipStream_t stream) {
    const float* x    = (const float*)d_in[0];
    const float* L_w  = (const float*)d_in[1];
    const float* UL_w = (const float*)d_in[2];
    const float* WQ   = (const float*)d_in[3];
    const float* WK   = (const float*)d_in[4];
    const float* WVd  = (const float*)d_in[5];
    const float* WVu  = (const float*)d_in[6];
    const float* WQ2  = (const float*)d_in[7];
    const float* WK2  = (const float*)d_in[8];
    const float* WVd2 = (const float*)d_in[9];
    const float* WVu2 = (const float*)d_in[10];
    const float* qin1 = (const float*)d_in[11];
    const float* qout1= (const float*)d_in[12];
    const float* qin2 = (const float*)d_in[13];
    const float* qout2= (const float*)d_in[14];
    float* out = (float*)d_out;
    float* POSb = (float*)d_ws;   // [0,1280) POS ; [1280,6400) Z

    int B = in_sizes[0] / (TS * 4);
    size_t lds_bytes = (size_t)LDS_FLOATS * sizeof(float);

    (void)hipFuncSetAttribute((const void*)trans_fused,
                              hipFuncAttributeMaxDynamicSharedMemorySize,
                              (int)lds_bytes);

    pre_kernel<<<dim3(1), dim3(256), 0, stream>>>(POSb, qin2, qout2, UL_w);
    trans_fused<<<dim3(B / BT), dim3(NTHR), lds_bytes, stream>>>(
        x, L_w, UL_w, WQ, WK, WVd, WVu, WQ2, WK2, WVd2, WVu2,
        qin1, qout1, qin2, qout2, POSb, out);
}

// Round 10
// 1370.518 us; speedup vs baseline: 1.0105x; 1.0105x over previous
//
#include <hip/hip_runtime.h>
#include <math.h>

#define TS 10
#define TD 128
#define TE 64
#define BT 8
#define NTHR 256
#define HSTR 132          // floats per Hs row: 128+4 pad
#define QSTR 68           // floats per Q/K/Vd/G/t row: 64+4 pad
#define NHROWS (TS*BT)    // 80

#define HS_FLOATS (NHROWS*HSTR)    // 10560
#define BUF_FLOATS (40*QSTR)       // 2720 (half-batch 40-row buffer)
#define P_FLOATS (BT*TS*12)        // 960
#define LDS_FLOATS (HS_FLOATS + 3*BUF_FLOATS + P_FLOATS)   // 19680 -> 78720 B (2 WG/CU)

#define INVSQRT10 0.31622776601683794f

typedef float v2f __attribute__((ext_vector_type(2)));

// Broadcast-free packed FMA via VOP3P op_sel (bit-identical IEEE fp32 fma),
// R7-proven correct AND the key to spill-free deep prefetch: removing the
// explicit broadcast temporaries keeps the allocator at exactly 128 VGPR
// (R7: WRITE_SIZE 5.1MB = zero scratch; compiler version: 21-23MB scratch).
//   PKFMA_LO: acc += a.lo * (w0,w1) ;  PKFMA_HI: acc += a.hi * (w0,w1)
#define PKFMA_LO(acc_, ap_, wp_) \
    asm("v_pk_fma_f32 %0, %1, %2, %0 op_sel:[0,0,0] op_sel_hi:[0,1,1]" \
        : "+v"(acc_) : "v"(ap_), "v"(wp_))
#define PKFMA_HI(acc_, ap_, wp_) \
    asm("v_pk_fma_f32 %0, %1, %2, %0 op_sel:[1,0,0] op_sel_hi:[1,1,1]" \
        : "+v"(acc_) : "v"(ap_), "v"(wp_))

// ---------------- pre-kernel (once per launch, into d_ws) -------------------
// ws layout: [0,1280) POS[10][128];  [1280,6400) Z[n][c][j] (10 x 4 x 128).
//   P2[n][c][i] = sum_d qout2[n][i][d] * UL_w[d][c]        (held in registers)
//   Z[n][c][j]  = sum_i qin2[n][j][i] * P2[n][c][i]
// so out[b][n][c] = sum_j E22[b][n][j] * Z[n][c][j] — the entire layer-2
// quesin2/quesout2/UL_w pipeline collapses into one K=128 dot per output
// (-16.2% of kernel FMAs, -654KB/WG of weight streaming). R9-verified.
__global__ void pre_kernel(float* __restrict__ ws,
                           const float* __restrict__ qin2,
                           const float* __restrict__ qout2,
                           const float* __restrict__ UL_w) {
    int tid = threadIdx.x;
    for (int idx = tid; idx < TS * TD; idx += 256) {
        int n = idx / TD, d = idx % TD;
        int j = d >> 1;
        double ang = (double)n / pow(1000.0, 2.0 * (double)j / (double)TD);
        double v = (d & 1) ? cos(ang) : sin(ang);
        ws[idx] = (float)v;
    }
    if (tid < TS * 4) {
        int n = tid >> 2, c = tid & 3;
        float p2r[TE];
#pragma unroll 4
        for (int i = 0; i < TE; i++) {
            const float* qp = qout2 + ((size_t)n * TE + i) * TD;
            float acc = 0.f;
            for (int d = 0; d < TD; d += 4) {
                float4 q4 = *(const float4*)(qp + d);
                acc = fmaf(q4.x, UL_w[(d + 0) * 4 + c], acc);
                acc = fmaf(q4.y, UL_w[(d + 1) * 4 + c], acc);
                acc = fmaf(q4.z, UL_w[(d + 2) * 4 + c], acc);
                acc = fmaf(q4.w, UL_w[(d + 3) * 4 + c], acc);
            }
            p2r[i] = acc;
        }
        float* zr = ws + TS * TD + (n * 4 + c) * TD;
#pragma unroll 4
        for (int j = 0; j < TD; j++) {
            const float* ip = qin2 + ((size_t)n * TD + j) * TE;
            float acc = 0.f;
            for (int i = 0; i < TE; i += 4) {
                float4 q4 = *(const float4*)(ip + i);
                acc = fmaf(q4.x, p2r[i + 0], acc);
                acc = fmaf(q4.y, p2r[i + 1], acc);
                acc = fmaf(q4.z, p2r[i + 2], acc);
                acc = fmaf(q4.w, p2r[i + 3], acc);
            }
            zr[j] = acc;
        }
    }
}

// ---------------- M-row x C-col fp32 GEMM tile, packed-pair FMAs ------------
// OUT[m][c] = sum_k A[row(m)+k] * W[k*ws+c]. A,O in LDS; W in global.
// K multiple of 16. Deep W-prefetch (R5/R6): W loads issue a full 8-k block
// (~256 compute-cycles at M=8/C=4) before first use, covering ~200cyc L2-hit
// latency. A is a 4-k LDS double-buffer (~120cyc <= 128cyc cover).
// Inner products via op_sel inline-asm pk-fma (R7): zero broadcast movs,
// zero scratch at the 128-VGPR cap. Summation order identical to scalar form.
template <int M, int SPLIT, int C, int K, bool ADD>
__device__ __forceinline__ void gemm_f32(
    const float* __restrict__ Ap, int a0, int aHi, int aLo,
    const float* __restrict__ W, int ws,
    float* __restrict__ Op, int o0, int oHi, int oLo,
    float scale)
{
    static_assert(C % 4 == 0, "C must be a multiple of 4");
    static_assert(K % 16 == 0 && K >= 32, "K must be a multiple of 16, >=32");
    constexpr int CG = C / 4;   // float4 groups
    constexpr int CP = C / 2;   // float2 pairs
    v2f acc[M][CP];
#pragma unroll
    for (int m = 0; m < M; m++)
#pragma unroll
        for (int p = 0; p < CP; p++) acc[m][p] = (v2f)(0.f);

    float4 aR0[M], aR1[M];
    float4 wA[8 * CG], wB[8 * CG];      // ping-pong 8-k W buffers
    const float* ap = Ap + a0;
    const float* wp = W;

    auto loadW8 = [&](float4* wR, const float* w) {
#pragma unroll
        for (int kk = 0; kk < 8; kk++)
#pragma unroll
            for (int cg = 0; cg < CG; cg++)
                wR[kk * CG + cg] = *(const float4*)(w + kk * ws + cg * 4);
    };
    auto loadA = [&](float4* aR, const float* a) {
#pragma unroll
        for (int m = 0; m < M; m++)
            aR[m] = *(const float4*)(a + (m / SPLIT) * aHi + (m % SPLIT) * aLo);
    };
    // 4 consecutive k-steps from wR[0..4*CG): k-pairs via op_sel broadcast.
    auto computeH = [&](const float4* aR, const float4* wR) {
#pragma unroll
        for (int m = 0; m < M; m++) {
            const v2f* ap2 = (const v2f*)&aR[m];    // (a0,a1),(a2,a3)
#pragma unroll
            for (int kp = 0; kp < 2; kp++) {
                const v2f* wf0 = (const v2f*)&wR[(2 * kp + 0) * CG];
                const v2f* wf1 = (const v2f*)&wR[(2 * kp + 1) * CG];
#pragma unroll
                for (int p = 0; p < CP; p++) {
                    PKFMA_LO(acc[m][p], ap2[kp], wf0[p]);   // k = 2kp
                    PKFMA_HI(acc[m][p], ap2[kp], wf1[p]);   // k = 2kp+1
                }
            }
        }
    };

    loadW8(wA, wp);          // k rows 0..7
    loadA(aR0, ap);          // k 0..3
#pragma unroll 1
    for (int k = 0; k + 16 < K; k += 16) {
        loadW8(wB, wp + 8 * ws);        // rows k+8..k+15 (used 2 computeH later)
        loadA(aR1, ap + 4);             // k+4..7
        computeH(aR0, wA);              // k..k+3
        loadA(aR0, ap + 8);             // k+8..11
        computeH(aR1, wA + 4 * CG);     // k+4..7
        loadW8(wA, wp + 16 * ws);       // rows k+16..k+23 (next iter / tail)
        loadA(aR1, ap + 12);            // k+12..15
        computeH(aR0, wB);              // k+8..11
        loadA(aR0, ap + 16);            // k+16..19
        computeH(aR1, wB + 4 * CG);     // k+12..15
        wp += 16 * ws; ap += 16;
    }
    // tail: final 16 k-steps (wA = rows k..k+7, aR0 = k..k+3)
    loadW8(wB, wp + 8 * ws);
    loadA(aR1, ap + 4);
    computeH(aR0, wA);
    loadA(aR0, ap + 8);
    computeH(aR1, wA + 4 * CG);
    loadA(aR1, ap + 12);
    computeH(aR0, wB);
    computeH(aR1, wB + 4 * CG);

    v2f s2; s2.x = scale; s2.y = scale;
#pragma unroll
    for (int m = 0; m < M; m++) {
        float* op = Op + o0 + (m / SPLIT) * oHi + (m % SPLIT) * oLo;
#pragma unroll
        for (int cg = 0; cg < CG; cg++) {
            float4 r;
            v2f* rp = (v2f*)&r;
            if constexpr (ADD) {
                float4 v = *(float4*)(op + cg * 4);
                const v2f* vp = (const v2f*)&v;
                rp[0] = s2 * acc[m][cg * 2 + 0] + vp[0];
                rp[1] = s2 * acc[m][cg * 2 + 1] + vp[1];
            } else {
                rp[0] = s2 * acc[m][cg * 2 + 0];
                rp[1] = s2 * acc[m][cg * 2 + 1];
            }
            *(float4*)(op + cg * 4) = r;
        }
    }
}

// ---------------- fused kernel ----------------------------------------------
// BT=8, hb-split, 78.72 KB LDS -> 2 WG/CU (LDS-limited), REQUIRES VGPR<=128
// (residency cliff at 128/129 — R5). launch_bounds(256,2) pins the cap at 128
// (R0/R6/R7-proven); arg>=4 caps at 64 and spills catastrophically (R1/R3).
// R10 = R9's Z-fused layer-2 + R7's op_sel spill-free gemm.
extern "C" __global__ __launch_bounds__(NTHR, 2)
void trans_fused(const float* __restrict__ x,
                 const float* __restrict__ L_w, const float* __restrict__ UL_w,
                 const float* __restrict__ WQ,  const float* __restrict__ WK,
                 const float* __restrict__ WVd, const float* __restrict__ WVu,
                 const float* __restrict__ WQ2, const float* __restrict__ WK2,
                 const float* __restrict__ WVd2,const float* __restrict__ WVu2,
                 const float* __restrict__ qin1,const float* __restrict__ qout1,
                 const float* __restrict__ qin2,const float* __restrict__ qout2,
                 const float* __restrict__ POSb, float* __restrict__ out)
{
    extern __shared__ float lds[];
    float* Hs = lds;                      // [80][HSTR], row = b*10 + n
    float* Qb = lds + HS_FLOATS;          // [40][QSTR], row r2 = b4*10 + n ; also G, t(lo)
    float* Kb = Qb + BUF_FLOATS;          // [40][QSTR]                     ; also t(hi)
    float* Vb = Kb + BUF_FLOATS;          // [40][QSTR] Vd
    float* Pb = Vb + BUF_FLOATS;          // [8][10][12] logits -> softmax weights
    float* Tb = Qb;                       // t: 80 rows spanning Qb+Kb

    const int tid = threadIdx.x;
    const int vtid = (tid + ((blockIdx.x & 3) << 6)) & 255;  // rotate idle windows
    const int gb0 = blockIdx.x * BT;
    const float* Zb = POSb + TS * TD;     // Z[n][c][j] (10 x 4 x 128)

    // ---- Phase 0: h = x @ L_w + POS (fp32; 4-term dot, packed) ----
    for (int idx = tid; idx < NHROWS * 32; idx += NTHR) {
        int r = idx >> 5, dg = (idx & 31) << 2;
        int b = r / 10, n = r - b * 10;
        const float* xp = x + ((size_t)(gb0 + b) * TS + n) * 4;
        float4 xv = *(const float4*)xp;
        const float* xf = (const float*)&xv;
        float4 p4 = *(const float4*)(POSb + n * TD + dg);
        v2f acc0 = ((const v2f*)&p4)[0], acc1 = ((const v2f*)&p4)[1];
#pragma unroll
        for (int c = 0; c < 4; c++) {
            float4 lw = *(const float4*)(L_w + c * TD + dg);
            v2f xb; xb.x = xf[c]; xb.y = xf[c];
            acc0 = xb * ((const v2f*)&lw)[0] + acc0;
            acc1 = xb * ((const v2f*)&lw)[1] + acc1;
        }
        float4 r4;
        ((v2f*)&r4)[0] = acc0; ((v2f*)&r4)[1] = acc1;
        *(float4*)(Hs + r * HSTR + dg) = r4;
    }
    __syncthreads();

    for (int layer = 0; layer < 2; ++layer) {
        const float* pWQ  = layer ? WQ2  : WQ;
        const float* pWK  = layer ? WK2  : WK;
        const float* pWVd = layer ? WVd2 : WVd;
        const float* pWVu = layer ? WVu2 : WVu;

        for (int hb = 0; hb < 2; ++hb) {
            // batches b = hb*4 + b4; Hs rows (hb*4+b4)*10 + n
            // ---- QKV: 240 tasks = mat(3) x np(5) x cg(16); M=8 = b4(4) x (n,n+5) ----
            if (vtid < 240) {
                int p = vtid / 80, t2 = vtid % 80;
                int np = t2 >> 4, cg = t2 & 15;
                const float* Wp = (p == 0 ? pWQ : (p == 1 ? pWK : pWVd)) + cg * 4;
                float* Ob = (p == 0 ? Qb : (p == 1 ? Kb : Vb));
                gemm_f32<8, 2, 4, TD, false>(
                    Hs, (hb * 40 + np) * HSTR, 10 * HSTR, 5 * HSTR,
                    Wp, TE,
                    Ob, np * QSTR + cg * 4, 10 * QSTR, 5 * QSTR, 1.f);
            }
            __syncthreads();

            // ---- logits (fp32, 2x2 packed chains): 220 = b4(4) x 55 (i,j<=i) ----
            if (vtid < 220) {
                int b4 = vtid / 55, pr = vtid % 55;
                int i = 0, base = 0;
                while (pr >= base + i + 1) { base += i + 1; i++; }
                int j = pr - base;
                const float* qr = Qb + (b4 * 10 + i) * QSTR;
                const float* kr = Kb + (b4 * 10 + j) * QSTR;
                v2f s0 = (v2f)(0.f), s1 = (v2f)(0.f);
                for (int e = 0; e < TE; e += 8) {
                    float4 qa = *(const float4*)(qr + e);
                    float4 ka = *(const float4*)(kr + e);
                    float4 qc = *(const float4*)(qr + e + 4);
                    float4 kc = *(const float4*)(kr + e + 4);
                    s0 = ((const v2f*)&qa)[0] * ((const v2f*)&ka)[0] + s0;
                    s1 = ((const v2f*)&qa)[1] * ((const v2f*)&ka)[1] + s1;
                    s0 = ((const v2f*)&qc)[0] * ((const v2f*)&kc)[0] + s0;
                    s1 = ((const v2f*)&qc)[1] * ((const v2f*)&kc)[1] + s1;
                }
                Pb[(hb * 4 + b4) * 120 + i * 12 + j] = (s0.x + s0.y) + (s1.x + s1.y);
            }
            __syncthreads();

            // ---- softmax over keys j<=i (fp32, matches reference) ----
            if (vtid < 40) {
                int b4 = vtid / 10, i = vtid % 10;
                float* pr = Pb + (hb * 4 + b4) * 120 + i * 12;
                float m = pr[0];
#pragma unroll
                for (int j = 1; j < TS; j++) if (j <= i) m = fmaxf(m, pr[j]);
                float sum = 0.f;
#pragma unroll
                for (int j = 0; j < TS; j++) if (j <= i) { float e = expf(pr[j] - m); pr[j] = e; sum += e; }
#pragma unroll
                for (int j = 0; j < TS; j++) pr[j] = (j <= i) ? pr[j] / sum : 0.f;
            }
            __syncthreads();

            // ---- G[r2=b4*10+q][e] = sum_k P * Vd[b4*10+k][e]; into Qb (Q dead) ----
            for (int oi = vtid; oi < 40 * 16; oi += NTHR) {
                int rr = oi >> 4, e4 = (oi & 15) * 4;
                int b4 = rr / 10, q = rr - b4 * 10;
                const float* pp = Pb + (hb * 4 + b4) * 120 + q * 12;
                v2f g0 = (v2f)(0.f), g1 = (v2f)(0.f);
#pragma unroll
                for (int k = 0; k < TS; k++) {
                    float p = pp[k];
                    v2f pv; pv.x = p; pv.y = p;
                    float4 v = *(const float4*)(Vb + (b4 * 10 + k) * QSTR + e4);
                    g0 = pv * ((const v2f*)&v)[0] + g0;
                    g1 = pv * ((const v2f*)&v)[1] + g1;
                }
                float4 g;
                ((v2f*)&g)[0] = g0; ((v2f*)&g)[1] = g1;
                *(float4*)(Qb + rr * QSTR + e4) = g;
            }
            __syncthreads();

            // ---- DE: Hs(half) += invsqrt10 * G @ WVu ----
            // 256 tasks exactly: b4(4) x qp(2) x cg(32); M=5 contiguous q rows.
            {
                int b4 = vtid >> 6, t2 = vtid & 63;
                int qp = t2 >> 5, cg = t2 & 31;
                gemm_f32<5, 5, 4, TE, true>(
                    Qb, (b4 * 10 + qp * 5) * QSTR, 0, QSTR,
                    pWVu + cg * 4, TD,
                    Hs, (hb * 40 + b4 * 10 + qp * 5) * HSTR + cg * 4, 0, HSTR,
                    INVSQRT10);
            }
            __syncthreads();
        } // hb

        if (layer == 0) {
            // ---- ques-in: t[80][64] = Hs @ quesin1[n]; 160 = n(10) x cg(16), M=8 ----
            if (vtid < 160) {
                int n = vtid >> 4, cg = vtid & 15;
                gemm_f32<8, 1, 4, TD, false>(
                    Hs, n * HSTR, 10 * HSTR, 0,
                    qin1 + (size_t)n * TD * TE + cg * 4, TE,
                    Tb, n * QSTR + cg * 4, 10 * QSTR, 0, 1.f);
            }
            __syncthreads();

            // ---- ques-out: Hs = t @ quesout1[n]; 320 = n(10) x cg(32), M=8 C=4 ----
            for (int task = vtid; task < 320; task += NTHR) {
                int n = task >> 5, cg = task & 31;
                gemm_f32<8, 1, 4, TE, false>(
                    Tb, n * QSTR, 10 * QSTR, 0,
                    qout1 + (size_t)n * TE * TD + cg * 4, TD,
                    Hs, n * HSTR + cg * 4, 10 * HSTR, 0, 1.f);
            }
            __syncthreads();
        } else {
            // ---- out[b][n][c] = E22 row . Z[n][c][:] (K=128); 320 tasks ----
            for (int idx = vtid; idx < NHROWS * 4; idx += NTHR) {
                int r = idx >> 2, c = idx & 3;
                int b = r / 10, n = r - b * 10;
                const float* hr = Hs + r * HSTR;
                const float* zr = Zb + (n * 4 + c) * TD;
                v2f s0 = (v2f)(0.f), s1 = (v2f)(0.f);
                for (int d = 0; d < TD; d += 4) {
                    float4 h4 = *(const float4*)(hr + d);
                    float4 z4 = *(const float4*)(zr + d);
                    s0 = ((const v2f*)&h4)[0] * ((const v2f*)&z4)[0] + s0;
                    s1 = ((const v2f*)&h4)[1] * ((const v2f*)&z4)[1] + s1;
                }
                out[((size_t)(gb0 + b) * TS + n) * 4 + c] = (s0.x + s0.y) + (s1.x + s1.y);
            }
        }
    } // layer
}

// ---------------- host launch -----------------------------------------------
extern "C" void kernel_launch(void* const* d_in, const int* in_sizes, int n_in,
                              void* d_out, int out_size, void* d_ws, size_t ws_size,
                              hipStream_t stream) {
    const float* x    = (const float*)d_in[0];
    const float* L_w  = (const float*)d_in[1];
    const float* UL_w = (const float*)d_in[2];
    const float* WQ   = (const float*)d_in[3];
    const float* WK   = (const float*)d_in[4];
    const float* WVd  = (const float*)d_in[5];
    const float* WVu  = (const float*)d_in[6];
    const float* WQ2  = (const float*)d_in[7];
    const float* WK2  = (const float*)d_in[8];
    const float* WVd2 = (const float*)d_in[9];
    const float* WVu2 = (const float*)d_in[10];
    const float* qin1 = (const float*)d_in[11];
    const float* qout1= (const float*)d_in[12];
    const float* qin2 = (const float*)d_in[13];
    const float* qout2= (const float*)d_in[14];
    float* out = (float*)d_out;
    float* POSb = (float*)d_ws;   // [0,1280) POS ; [1280,6400) Z

    int B = in_sizes[0] / (TS * 4);
    size_t lds_bytes = (size_t)LDS_FLOATS * sizeof(float);

    (void)hipFuncSetAttribute((const void*)trans_fused,
                              hipFuncAttributeMaxDynamicSharedMemorySize,
                              (int)lds_bytes);

    pre_kernel<<<dim3(1), dim3(256), 0, stream>>>(POSb, qin2, qout2, UL_w);
    trans_fused<<<dim3(B / BT), dim3(NTHR), lds_bytes, stream>>>(
        x, L_w, UL_w, WQ, WK, WVd, WVu, WQ2, WK2, WVd2, WVu2,
        qin1, qout1, qin2, qout2, POSb, out);
}

// Round 11
// 833.169 us; speedup vs baseline: 1.6622x; 1.6449x over previous
//
#include <hip/hip_runtime.h>
#include <math.h>

#define TS 10
#define TD 128
#define TE 64
#define BT 8
#define NTHR 256
#define HSTR 132          // floats per Hs row: 128+4 pad
#define QSTR 68           // floats per Q/K/Vd/G/t row: 64+4 pad
#define NHROWS (TS*BT)    // 80

#define HS_FLOATS (NHROWS*HSTR)    // 10560
#define BUF_FLOATS (40*QSTR)       // 2720 (half-batch 40-row buffer)
#define P_FLOATS (BT*TS*12)        // 960
#define LDS_FLOATS (HS_FLOATS + 3*BUF_FLOATS + P_FLOATS)   // 19680 -> 78720 B (2 WG/CU)

#define INVSQRT10 0.31622776601683794f

// workspace float offsets
#define WS_POS 0          // POS[10][128]            (1280)
#define WS_Z   1280       // Z[n][c][j] 10x4x128     (5120)
#define WS_LW  6400       // LW[p][c][e] 3x4x64      (768)
#define WS_PW  7168       // PW[p][n][e] 3x10x64     (1920)
                          // total 9088 floats = 36.4 KB

typedef float v2f __attribute__((ext_vector_type(2)));

// Broadcast-free packed FMA via VOP3P op_sel (bit-identical IEEE fp32 fma),
// R7-proven correct AND the key to spill-free deep prefetch (R10: WRITE_SIZE
// = exact output, VGPR = 128).
#define PKFMA_LO(acc_, ap_, wp_) \
    asm("v_pk_fma_f32 %0, %1, %2, %0 op_sel:[0,0,0] op_sel_hi:[0,1,1]" \
        : "+v"(acc_) : "v"(ap_), "v"(wp_))
#define PKFMA_HI(acc_, ap_, wp_) \
    asm("v_pk_fma_f32 %0, %1, %2, %0 op_sel:[1,0,0] op_sel_hi:[1,1,1]" \
        : "+v"(acc_) : "v"(ap_), "v"(wp_))

// ---------------- pre-kernel (once per launch, into d_ws) -------------------
// Fully 256-thread-parallel (R10's 40-thread serial Z pass was ~27us and the
// widest window for environmental stall outliers).
//   POS[n][d]                                   (fp64, reference-exact)
//   P2[n][c][i] = sum_d qout2[n][i][d]*UL_w[d][c]      (LDS)
//   Z[n][c][j]  = sum_i qin2[n][j][i]*P2[n][c][i]      -> layer-2 ques+UL fold
//   LW[p][c][e] = sum_d L_w[c][d]*Wp[d][e]             -> rank-4 QKV fold
//   PW[p][n][e] = sum_d POS[n][d]*Wp[d][e]
// Layer-1 QKV then costs K=4 instead of K=128 (-27.7% of kernel FMAs).
__global__ void pre_kernel(float* __restrict__ ws,
                           const float* __restrict__ L_w,
                           const float* __restrict__ WQ,
                           const float* __restrict__ WK,
                           const float* __restrict__ WVd,
                           const float* __restrict__ qin2,
                           const float* __restrict__ qout2,
                           const float* __restrict__ UL_w) {
    __shared__ float sPOS[TS * TD];      // 1280
    __shared__ float sP2[TS * 4 * TE];   // 2560
    const int tid = threadIdx.x;

    // POS (fp64, matches reference constant table)
    for (int idx = tid; idx < TS * TD; idx += 256) {
        int n = idx / TD, d = idx % TD;
        int j = d >> 1;
        double ang = (double)n / pow(1000.0, 2.0 * (double)j / (double)TD);
        float v = (float)((d & 1) ? cos(ang) : sin(ang));
        sPOS[idx] = v;
        ws[WS_POS + idx] = v;
    }
    // P2: 2560 items, K=128
    for (int idx = tid; idx < TS * 4 * TE; idx += 256) {
        int n = idx >> 8, r = idx & 255, c = r >> 6, i = r & 63;
        const float* qp = qout2 + ((size_t)n * TE + i) * TD;
        float acc = 0.f;
        for (int d = 0; d < TD; d += 4) {
            float4 q4 = *(const float4*)(qp + d);
            acc = fmaf(q4.x, UL_w[(d + 0) * 4 + c], acc);
            acc = fmaf(q4.y, UL_w[(d + 1) * 4 + c], acc);
            acc = fmaf(q4.z, UL_w[(d + 2) * 4 + c], acc);
            acc = fmaf(q4.w, UL_w[(d + 3) * 4 + c], acc);
        }
        sP2[idx] = acc;
    }
    __syncthreads();
    // Z: 5120 items, K=64 (reads sP2)
    for (int idx = tid; idx < TS * 4 * TD; idx += 256) {
        int n = idx >> 9, r = idx & 511, c = r >> 7, j = r & 127;
        const float* ip = qin2 + ((size_t)n * TD + j) * TE;
        const float* pp = sP2 + (n * 4 + c) * TE;
        float acc = 0.f;
        for (int i = 0; i < TE; i += 4) {
            float4 q4 = *(const float4*)(ip + i);
            acc = fmaf(q4.x, pp[i + 0], acc);
            acc = fmaf(q4.y, pp[i + 1], acc);
            acc = fmaf(q4.z, pp[i + 2], acc);
            acc = fmaf(q4.w, pp[i + 3], acc);
        }
        ws[WS_Z + idx] = acc;
    }
    // LW[p][c][e]: 768 items, K=128
    for (int idx = tid; idx < 3 * 4 * TE; idx += 256) {
        int p = idx >> 8, r = idx & 255, c = r >> 6, e = r & 63;
        const float* Wp = (p == 0 ? WQ : (p == 1 ? WK : WVd));
        const float* lr = L_w + c * TD;
        float acc = 0.f;
        for (int d = 0; d < TD; d++) acc = fmaf(lr[d], Wp[d * TE + e], acc);
        ws[WS_LW + idx] = acc;
    }
    // PW[p][n][e]: 1920 items, K=128 (reads sPOS)
    for (int idx = tid; idx < 3 * TS * TE; idx += 256) {
        int p = idx / 640, r = idx % 640, n = r >> 6, e = r & 63;
        const float* Wp = (p == 0 ? WQ : (p == 1 ? WK : WVd));
        const float* pr = sPOS + n * TD;
        float acc = 0.f;
        for (int d = 0; d < TD; d++) acc = fmaf(pr[d], Wp[d * TE + e], acc);
        ws[WS_PW + idx] = acc;
    }
}

// ---------------- M-row x C-col fp32 GEMM tile, packed-pair FMAs ------------
// OUT[m][c] = sum_k A[row(m)+k] * W[k*ws+c]. A,O in LDS; W in global.
// K multiple of 16. Deep W-prefetch (R5/R6): W loads issue a full 8-k block
// (~256 compute-cycles at M=8/C=4) before first use, covering ~200cyc L2-hit
// latency. A is a 4-k LDS double-buffer (~120cyc <= 128cyc cover).
// Inner products via op_sel inline-asm pk-fma (R7): zero broadcast movs,
// zero scratch at the 128-VGPR cap. Summation order identical to scalar form.
template <int M, int SPLIT, int C, int K, bool ADD>
__device__ __forceinline__ void gemm_f32(
    const float* __restrict__ Ap, int a0, int aHi, int aLo,
    const float* __restrict__ W, int ws,
    float* __restrict__ Op, int o0, int oHi, int oLo,
    float scale)
{
    static_assert(C % 4 == 0, "C must be a multiple of 4");
    static_assert(K % 16 == 0 && K >= 32, "K must be a multiple of 16, >=32");
    constexpr int CG = C / 4;   // float4 groups
    constexpr int CP = C / 2;   // float2 pairs
    v2f acc[M][CP];
#pragma unroll
    for (int m = 0; m < M; m++)
#pragma unroll
        for (int p = 0; p < CP; p++) acc[m][p] = (v2f)(0.f);

    float4 aR0[M], aR1[M];
    float4 wA[8 * CG], wB[8 * CG];      // ping-pong 8-k W buffers
    const float* ap = Ap + a0;
    const float* wp = W;

    auto loadW8 = [&](float4* wR, const float* w) {
#pragma unroll
        for (int kk = 0; kk < 8; kk++)
#pragma unroll
            for (int cg = 0; cg < CG; cg++)
                wR[kk * CG + cg] = *(const float4*)(w + kk * ws + cg * 4);
    };
    auto loadA = [&](float4* aR, const float* a) {
#pragma unroll
        for (int m = 0; m < M; m++)
            aR[m] = *(const float4*)(a + (m / SPLIT) * aHi + (m % SPLIT) * aLo);
    };
    // 4 consecutive k-steps from wR[0..4*CG): k-pairs via op_sel broadcast.
    auto computeH = [&](const float4* aR, const float4* wR) {
#pragma unroll
        for (int m = 0; m < M; m++) {
            const v2f* ap2 = (const v2f*)&aR[m];    // (a0,a1),(a2,a3)
#pragma unroll
            for (int kp = 0; kp < 2; kp++) {
                const v2f* wf0 = (const v2f*)&wR[(2 * kp + 0) * CG];
                const v2f* wf1 = (const v2f*)&wR[(2 * kp + 1) * CG];
#pragma unroll
                for (int p = 0; p < CP; p++) {
                    PKFMA_LO(acc[m][p], ap2[kp], wf0[p]);   // k = 2kp
                    PKFMA_HI(acc[m][p], ap2[kp], wf1[p]);   // k = 2kp+1
                }
            }
        }
    };

    loadW8(wA, wp);          // k rows 0..7
    loadA(aR0, ap);          // k 0..3
#pragma unroll 1
    for (int k = 0; k + 16 < K; k += 16) {
        loadW8(wB, wp + 8 * ws);        // rows k+8..k+15 (used 2 computeH later)
        loadA(aR1, ap + 4);             // k+4..7
        computeH(aR0, wA);              // k..k+3
        loadA(aR0, ap + 8);             // k+8..11
        computeH(aR1, wA + 4 * CG);     // k+4..7
        loadW8(wA, wp + 16 * ws);       // rows k+16..k+23 (next iter / tail)
        loadA(aR1, ap + 12);            // k+12..15
        computeH(aR0, wB);              // k+8..11
        loadA(aR0, ap + 16);            // k+16..19
        computeH(aR1, wB + 4 * CG);     // k+12..15
        wp += 16 * ws; ap += 16;
    }
    // tail: final 16 k-steps (wA = rows k..k+7, aR0 = k..k+3)
    loadW8(wB, wp + 8 * ws);
    loadA(aR1, ap + 4);
    computeH(aR0, wA);
    loadA(aR0, ap + 8);
    computeH(aR1, wA + 4 * CG);
    loadA(aR1, ap + 12);
    computeH(aR0, wB);
    computeH(aR1, wB + 4 * CG);

    v2f s2; s2.x = scale; s2.y = scale;
#pragma unroll
    for (int m = 0; m < M; m++) {
        float* op = Op + o0 + (m / SPLIT) * oHi + (m % SPLIT) * oLo;
#pragma unroll
        for (int cg = 0; cg < CG; cg++) {
            float4 r;
            v2f* rp = (v2f*)&r;
            if constexpr (ADD) {
                float4 v = *(float4*)(op + cg * 4);
                const v2f* vp = (const v2f*)&v;
                rp[0] = s2 * acc[m][cg * 2 + 0] + vp[0];
                rp[1] = s2 * acc[m][cg * 2 + 1] + vp[1];
            } else {
                rp[0] = s2 * acc[m][cg * 2 + 0];
                rp[1] = s2 * acc[m][cg * 2 + 1];
            }
            *(float4*)(op + cg * 4) = r;
        }
    }
}

// ---------------- fused kernel ----------------------------------------------
// BT=8, hb-split, 78.72 KB LDS -> 2 WG/CU (LDS-limited), REQUIRES VGPR<=128
// (residency cliff at 128/129 — R5). launch_bounds(256,2) pins the cap at 128
// (R0/R6/R7/R10-proven); arg>=4 caps at 64 and spills catastrophically.
// R11 = R10 + rank-4-factored layer-1 QKV (LW/PW tables from pre_kernel).
extern "C" __global__ __launch_bounds__(NTHR, 2)
void trans_fused(const float* __restrict__ x,
                 const float* __restrict__ L_w, const float* __restrict__ UL_w,
                 const float* __restrict__ WQ,  const float* __restrict__ WK,
                 const float* __restrict__ WVd, const float* __restrict__ WVu,
                 const float* __restrict__ WQ2, const float* __restrict__ WK2,
                 const float* __restrict__ WVd2,const float* __restrict__ WVu2,
                 const float* __restrict__ qin1,const float* __restrict__ qout1,
                 const float* __restrict__ qin2,const float* __restrict__ qout2,
                 const float* __restrict__ POSb, float* __restrict__ out)
{
    extern __shared__ float lds[];
    float* Hs = lds;                      // [80][HSTR], row = b*10 + n
    float* Qb = lds + HS_FLOATS;          // [40][QSTR], row r2 = b4*10 + n ; also G, t(lo)
    float* Kb = Qb + BUF_FLOATS;          // [40][QSTR]                     ; also t(hi)
    float* Vb = Kb + BUF_FLOATS;          // [40][QSTR] Vd
    float* Pb = Vb + BUF_FLOATS;          // [8][10][12] logits -> softmax weights
    float* Tb = Qb;                       // t: 80 rows spanning Qb+Kb

    const int tid = threadIdx.x;
    const int vtid = (tid + ((blockIdx.x & 3) << 6)) & 255;  // rotate idle windows
    const int gb0 = blockIdx.x * BT;
    const float* Zb  = POSb + WS_Z;       // Z[n][c][j]
    const float* LWb = POSb + WS_LW;      // LW[p][c][e]
    const float* PWb = POSb + WS_PW;      // PW[p][n][e]

    // ---- Phase 0: h = x @ L_w + POS (fp32; 4-term dot, packed) ----
    for (int idx = tid; idx < NHROWS * 32; idx += NTHR) {
        int r = idx >> 5, dg = (idx & 31) << 2;
        int b = r / 10, n = r - b * 10;
        const float* xp = x + ((size_t)(gb0 + b) * TS + n) * 4;
        float4 xv = *(const float4*)xp;
        const float* xf = (const float*)&xv;
        float4 p4 = *(const float4*)(POSb + n * TD + dg);
        v2f acc0 = ((const v2f*)&p4)[0], acc1 = ((const v2f*)&p4)[1];
#pragma unroll
        for (int c = 0; c < 4; c++) {
            float4 lw = *(const float4*)(L_w + c * TD + dg);
            v2f xb; xb.x = xf[c]; xb.y = xf[c];
            acc0 = xb * ((const v2f*)&lw)[0] + acc0;
            acc1 = xb * ((const v2f*)&lw)[1] + acc1;
        }
        float4 r4;
        ((v2f*)&r4)[0] = acc0; ((v2f*)&r4)[1] = acc1;
        *(float4*)(Hs + r * HSTR + dg) = r4;
    }
    __syncthreads();

    for (int layer = 0; layer < 2; ++layer) {
        const float* pWQ  = layer ? WQ2  : WQ;
        const float* pWK  = layer ? WK2  : WK;
        const float* pWVd = layer ? WVd2 : WVd;
        const float* pWVu = layer ? WVu2 : WVu;

        for (int hb = 0; hb < 2; ++hb) {
            // batches b = hb*4 + b4; Hs rows (hb*4+b4)*10 + n
            if (layer == 0) {
                // ---- QKV layer-1, rank-4 factored: Q = x@LW + PW ----
                // 1920 tasks = p(3) x rr(40) x e4(16); K=4 + bias add.
                for (int t = vtid; t < 1920; t += NTHR) {
                    int p = t / 640, r2 = t % 640, rr = r2 >> 4, e4 = r2 & 15;
                    int b4 = rr / 10, n = rr - b4 * 10;
                    const float* xp = x + ((size_t)(gb0 + hb * 4 + b4) * TS + n) * 4;
                    float4 x4 = *(const float4*)xp;
                    const float* xf = (const float*)&x4;
                    const float* lw = LWb + p * 256 + e4 * 4;
                    float4 pw = *(const float4*)(PWb + p * 640 + n * 64 + e4 * 4);
                    v2f a0 = ((const v2f*)&pw)[0], a1 = ((const v2f*)&pw)[1];
#pragma unroll
                    for (int c = 0; c < 4; c++) {
                        float4 l4 = *(const float4*)(lw + c * 64);
                        v2f xb; xb.x = xf[c]; xb.y = xf[c];
                        a0 = xb * ((const v2f*)&l4)[0] + a0;
                        a1 = xb * ((const v2f*)&l4)[1] + a1;
                    }
                    float* Ob = (p == 0 ? Qb : (p == 1 ? Kb : Vb));
                    float4 r4;
                    ((v2f*)&r4)[0] = a0; ((v2f*)&r4)[1] = a1;
                    *(float4*)(Ob + rr * QSTR + e4 * 4) = r4;
                }
            } else {
                // ---- QKV layer-2: full-rank gemm, 240 tasks; M=8 ----
                if (vtid < 240) {
                    int p = vtid / 80, t2 = vtid % 80;
                    int np = t2 >> 4, cg = t2 & 15;
                    const float* Wp = (p == 0 ? pWQ : (p == 1 ? pWK : pWVd)) + cg * 4;
                    float* Ob = (p == 0 ? Qb : (p == 1 ? Kb : Vb));
                    gemm_f32<8, 2, 4, TD, false>(
                        Hs, (hb * 40 + np) * HSTR, 10 * HSTR, 5 * HSTR,
                        Wp, TE,
                        Ob, np * QSTR + cg * 4, 10 * QSTR, 5 * QSTR, 1.f);
                }
            }
            __syncthreads();

            // ---- logits (fp32, 2x2 packed chains): 220 = b4(4) x 55 (i,j<=i) ----
            if (vtid < 220) {
                int b4 = vtid / 55, pr = vtid % 55;
                int i = 0, base = 0;
                while (pr >= base + i + 1) { base += i + 1; i++; }
                int j = pr - base;
                const float* qr = Qb + (b4 * 10 + i) * QSTR;
                const float* kr = Kb + (b4 * 10 + j) * QSTR;
                v2f s0 = (v2f)(0.f), s1 = (v2f)(0.f);
                for (int e = 0; e < TE; e += 8) {
                    float4 qa = *(const float4*)(qr + e);
                    float4 ka = *(const float4*)(kr + e);
                    float4 qc = *(const float4*)(qr + e + 4);
                    float4 kc = *(const float4*)(kr + e + 4);
                    s0 = ((const v2f*)&qa)[0] * ((const v2f*)&ka)[0] + s0;
                    s1 = ((const v2f*)&qa)[1] * ((const v2f*)&ka)[1] + s1;
                    s0 = ((const v2f*)&qc)[0] * ((const v2f*)&kc)[0] + s0;
                    s1 = ((const v2f*)&qc)[1] * ((const v2f*)&kc)[1] + s1;
                }
                Pb[(hb * 4 + b4) * 120 + i * 12 + j] = (s0.x + s0.y) + (s1.x + s1.y);
            }
            __syncthreads();

            // ---- softmax over keys j<=i (fp32, matches reference) ----
            if (vtid < 40) {
                int b4 = vtid / 10, i = vtid % 10;
                float* pr = Pb + (hb * 4 + b4) * 120 + i * 12;
                float m = pr[0];
#pragma unroll
                for (int j = 1; j < TS; j++) if (j <= i) m = fmaxf(m, pr[j]);
                float sum = 0.f;
#pragma unroll
                for (int j = 0; j < TS; j++) if (j <= i) { float e = expf(pr[j] - m); pr[j] = e; sum += e; }
#pragma unroll
                for (int j = 0; j < TS; j++) pr[j] = (j <= i) ? pr[j] / sum : 0.f;
            }
            __syncthreads();

            // ---- G[r2=b4*10+q][e] = sum_k P * Vd[b4*10+k][e]; into Qb (Q dead) ----
            for (int oi = vtid; oi < 40 * 16; oi += NTHR) {
                int rr = oi >> 4, e4 = (oi & 15) * 4;
                int b4 = rr / 10, q = rr - b4 * 10;
                const float* pp = Pb + (hb * 4 + b4) * 120 + q * 12;
                v2f g0 = (v2f)(0.f), g1 = (v2f)(0.f);
#pragma unroll
                for (int k = 0; k < TS; k++) {
                    float p = pp[k];
                    v2f pv; pv.x = p; pv.y = p;
                    float4 v = *(const float4*)(Vb + (b4 * 10 + k) * QSTR + e4);
                    g0 = pv * ((const v2f*)&v)[0] + g0;
                    g1 = pv * ((const v2f*)&v)[1] + g1;
                }
                float4 g;
                ((v2f*)&g)[0] = g0; ((v2f*)&g)[1] = g1;
                *(float4*)(Qb + rr * QSTR + e4) = g;
            }
            __syncthreads();

            // ---- DE: Hs(half) += invsqrt10 * G @ WVu ----
            // 256 tasks exactly: b4(4) x qp(2) x cg(32); M=5 contiguous q rows.
            {
                int b4 = vtid >> 6, t2 = vtid & 63;
                int qp = t2 >> 5, cg = t2 & 31;
                gemm_f32<5, 5, 4, TE, true>(
                    Qb, (b4 * 10 + qp * 5) * QSTR, 0, QSTR,
                    pWVu + cg * 4, TD,
                    Hs, (hb * 40 + b4 * 10 + qp * 5) * HSTR + cg * 4, 0, HSTR,
                    INVSQRT10);
            }
            __syncthreads();
        } // hb

        if (layer == 0) {
            // ---- ques-in: t[80][64] = Hs @ quesin1[n]; 160 = n(10) x cg(16), M=8 ----
            if (vtid < 160) {
                int n = vtid >> 4, cg = vtid & 15;
                gemm_f32<8, 1, 4, TD, false>(
                    Hs, n * HSTR, 10 * HSTR, 0,
                    qin1 + (size_t)n * TD * TE + cg * 4, TE,
                    Tb, n * QSTR + cg * 4, 10 * QSTR, 0, 1.f);
            }
            __syncthreads();

            // ---- ques-out: Hs = t @ quesout1[n]; 320 = n(10) x cg(32), M=8 C=4 ----
            for (int task = vtid; task < 320; task += NTHR) {
                int n = task >> 5, cg = task & 31;
                gemm_f32<8, 1, 4, TE, false>(
                    Tb, n * QSTR, 10 * QSTR, 0,
                    qout1 + (size_t)n * TE * TD + cg * 4, TD,
                    Hs, n * HSTR + cg * 4, 10 * HSTR, 0, 1.f);
            }
            __syncthreads();
        } else {
            // ---- out[b][n][c] = E22 row . Z[n][c][:] (K=128); 320 tasks ----
            for (int idx = vtid; idx < NHROWS * 4; idx += NTHR) {
                int r = idx >> 2, c = idx & 3;
                int b = r / 10, n = r - b * 10;
                const float* hr = Hs + r * HSTR;
                const float* zr = Zb + (n * 4 + c) * TD;
                v2f s0 = (v2f)(0.f), s1 = (v2f)(0.f);
                for (int d = 0; d < TD; d += 4) {
                    float4 h4 = *(const float4*)(hr + d);
                    float4 z4 = *(const float4*)(zr + d);
                    s0 = ((const v2f*)&h4)[0] * ((const v2f*)&z4)[0] + s0;
                    s1 = ((const v2f*)&h4)[1] * ((const v2f*)&z4)[1] + s1;
                }
                out[((size_t)(gb0 + b) * TS + n) * 4 + c] = (s0.x + s0.y) + (s1.x + s1.y);
            }
        }
    } // layer
}

// ---------------- host launch -----------------------------------------------
extern "C" void kernel_launch(void* const* d_in, const int* in_sizes, int n_in,
                              void* d_out, int out_size, void* d_ws, size_t ws_size,
                              hipStream_t stream) {
    const float* x    = (const float*)d_in[0];
    const float* L_w  = (const float*)d_in[1];
    const float* UL_w = (const float*)d_in[2];
    const float* WQ   = (const float*)d_in[3];
    const float* WK   = (const float*)d_in[4];
    const float* WVd  = (const float*)d_in[5];
    const float* WVu  = (const float*)d_in[6];
    const float* WQ2  = (const float*)d_in[7];
    const float* WK2  = (const float*)d_in[8];
    const float* WVd2 = (const float*)d_in[9];
    const float* WVu2 = (const float*)d_in[10];
    const float* qin1 = (const float*)d_in[11];
    const float* qout1= (const float*)d_in[12];
    const float* qin2 = (const float*)d_in[13];
    const float* qout2= (const float*)d_in[14];
    float* out = (float*)d_out;
    float* POSb = (float*)d_ws;   // see WS_* layout (36.4 KB)

    int B = in_sizes[0] / (TS * 4);
    size_t lds_bytes = (size_t)LDS_FLOATS * sizeof(float);

    (void)hipFuncSetAttribute((const void*)trans_fused,
                              hipFuncAttributeMaxDynamicSharedMemorySize,
                              (int)lds_bytes);

    pre_kernel<<<dim3(1), dim3(256), 0, stream>>>(POSb, L_w, WQ, WK, WVd,
                                                  qin2, qout2, UL_w);
    trans_fused<<<dim3(B / BT), dim3(NTHR), lds_bytes, stream>>>(
        x, L_w, UL_w, WQ, WK, WVd, WVu, WQ2, WK2, WVd2, WVu2,
        qin1, qout1, qin2, qout2, POSb, out);
}